// Round 1
// baseline (2911.218 us; speedup 1.0000x reference)
//
#include <hip/hip_runtime.h>
#include <hip/hip_bf16.h>
#include <math.h>

// Problem constants
#define BB 4
#define TT 2048
#define CC 1024
#define NH 16
#define HD 64
#define C3 3072

// ---------------------------------------------------------------------------
// Tiled SGEMM: C[M,N] = A[M,K] @ B[K,N], row-major, all dims multiples of 64/16
// 256 threads, 64x64 block tile, BK=16, each thread computes 4x4.
// ---------------------------------------------------------------------------
__global__ __launch_bounds__(256) void sgemm64(const float* __restrict__ A,
                                               const float* __restrict__ B,
                                               float* __restrict__ C,
                                               int M, int N, int K) {
    __shared__ __align__(16) float As[16][68];  // As[k][m], stride 68 floats (16B-aligned rows)
    __shared__ __align__(16) float Bs[16][68];  // Bs[k][n]

    const int tid = threadIdx.x;
    const int tx = tid & 15;        // 0..15 -> col group
    const int ty = tid >> 4;        // 0..15 -> row group
    const int bm0 = blockIdx.y * 64;
    const int bn0 = blockIdx.x * 64;

    // A-load mapping: one float4 per thread (64 rows x 16 k)
    const int am = tid >> 2;          // 0..63 row within tile
    const int ak = (tid & 3) * 4;     // k offset 0,4,8,12
    // B-load mapping: one float4 per thread (16 k x 64 n)
    const int bk = tid >> 4;          // 0..15
    const int bn = (tid & 15) * 4;    // 0..60

    float acc[4][4] = {};

    for (int k0 = 0; k0 < K; k0 += 16) {
        float4 av = *(const float4*)(A + (size_t)(bm0 + am) * K + k0 + ak);
        float4 bv = *(const float4*)(B + (size_t)(k0 + bk) * N + bn0 + bn);
        As[ak + 0][am] = av.x;
        As[ak + 1][am] = av.y;
        As[ak + 2][am] = av.z;
        As[ak + 3][am] = av.w;
        *(float4*)&Bs[bk][bn] = bv;
        __syncthreads();
#pragma unroll
        for (int kk = 0; kk < 16; ++kk) {
            float4 a = *(const float4*)&As[kk][ty * 4];
            float4 b = *(const float4*)&Bs[kk][tx * 4];
            acc[0][0] = fmaf(a.x, b.x, acc[0][0]);
            acc[0][1] = fmaf(a.x, b.y, acc[0][1]);
            acc[0][2] = fmaf(a.x, b.z, acc[0][2]);
            acc[0][3] = fmaf(a.x, b.w, acc[0][3]);
            acc[1][0] = fmaf(a.y, b.x, acc[1][0]);
            acc[1][1] = fmaf(a.y, b.y, acc[1][1]);
            acc[1][2] = fmaf(a.y, b.z, acc[1][2]);
            acc[1][3] = fmaf(a.y, b.w, acc[1][3]);
            acc[2][0] = fmaf(a.z, b.x, acc[2][0]);
            acc[2][1] = fmaf(a.z, b.y, acc[2][1]);
            acc[2][2] = fmaf(a.z, b.z, acc[2][2]);
            acc[2][3] = fmaf(a.z, b.w, acc[2][3]);
            acc[3][0] = fmaf(a.w, b.x, acc[3][0]);
            acc[3][1] = fmaf(a.w, b.y, acc[3][1]);
            acc[3][2] = fmaf(a.w, b.z, acc[3][2]);
            acc[3][3] = fmaf(a.w, b.w, acc[3][3]);
        }
        __syncthreads();
    }

#pragma unroll
    for (int i = 0; i < 4; ++i) {
        float4 o = make_float4(acc[i][0], acc[i][1], acc[i][2], acc[i][3]);
        *(float4*)(C + (size_t)(bm0 + ty * 4 + i) * N + bn0 + tx * 4) = o;
    }
}

// ---------------------------------------------------------------------------
// RoPE (interleaved, lucidrains-style) applied in-place to q and k of qkv.
// Also folds the 1/sqrt(hd)=0.125 attention scale into q (exact pow2).
// grid: (B*T*512/256, 2); blockIdx.y==0 -> q, ==1 -> k.
// ---------------------------------------------------------------------------
__global__ __launch_bounds__(256) void rope_kernel(float* __restrict__ qkv) {
    int idx = blockIdx.x * 256 + threadIdx.x;   // pair index 0 .. B*T*512-1
    int isK = blockIdx.y;
    int c2 = idx & 511;       // h*32 + p
    int bt = idx >> 9;        // 0..B*T-1
    int t = bt & (TT - 1);
    int p = c2 & 31;

    // inv_freq = 10000^(-p/32); freqs = t * inv_freq (matches fp32 reference)
    float inv_freq = expf(-(float)p * (9.210340371976184f / 32.0f));
    float fr = (float)t * inv_freq;
    float s, c;
    sincosf(fr, &s, &c);

    size_t base = (size_t)bt * C3 + (size_t)isK * CC + 2 * c2;
    float x0 = qkv[base];
    float x1 = qkv[base + 1];
    float sc = isK ? 1.0f : 0.125f;
    qkv[base]     = (x0 * c - x1 * s) * sc;
    qkv[base + 1] = (x1 * c + x0 * s) * sc;
}

// ---------------------------------------------------------------------------
// Flash-style causal attention. hd=64 == wavefront size.
// Block = 256 threads = 4 waves; each wave owns 2 queries; block owns 8
// consecutive queries of one (b,h). LDS K-tile (64 keys) + transposed V-tile.
// Score phase: lane = key. PV phase: lane = output dim. Online softmax.
// grid.x = B*H*(T/8); slow dim = (b,h) for K/V L2 locality.
// ---------------------------------------------------------------------------
__global__ __launch_bounds__(256) void attn_kernel(const float* __restrict__ qkv,
                                                   float* __restrict__ y) {
    __shared__ float Kt[64][65];    // Kt[j][d]
    __shared__ float VtT[64][65];   // VtT[d][j]  (transposed on store)
    __shared__ float qs[4][2][64];
    __shared__ float ps[4][2][64];

    const int tid = threadIdx.x;
    const int w = tid >> 6;
    const int lane = tid & 63;

    const int bh = blockIdx.x >> 8;           // / (T/8 = 256)
    const int qb = (blockIdx.x & 255) * 8;
    const int b = bh >> 4;
    const int h = bh & 15;

    const int q0 = qb + w * 2;
    const int q1 = q0 + 1;

    // load q rows (already rope'd and pre-scaled by 0.125)
    qs[w][0][lane] = qkv[((size_t)(b * TT + q0)) * C3 + h * HD + lane];
    qs[w][1][lane] = qkv[((size_t)(b * TT + q1)) * C3 + h * HD + lane];

    float m0 = -INFINITY, m1 = -INFINITY;
    float l0 = 0.f, l1 = 0.f;
    float O0 = 0.f, O1 = 0.f;

    const int nt = qb / 64 + 1;   // all 8 queries in block need same tile count

    for (int jt = 0; jt < nt; ++jt) {
        __syncthreads();
        // cooperative K/V tile load (64 keys x 64 dims each); V transposed
#pragma unroll
        for (int it = 0; it < 16; ++it) {
            int idx = it * 256 + tid;
            int j = idx >> 6;
            int d = idx & 63;
            const float* src = qkv + ((size_t)(b * TT + jt * 64 + j)) * C3 + h * HD + d;
            Kt[j][d] = src[CC];        // K
            VtT[d][j] = src[2 * CC];   // V transposed
        }
        __syncthreads();

        // --- score phase: lane = key j ---
        float s0 = 0.f, s1 = 0.f;
#pragma unroll
        for (int d = 0; d < 64; ++d) {
            float kv = Kt[lane][d];
            s0 = fmaf(qs[w][0][d], kv, s0);
            s1 = fmaf(qs[w][1][d], kv, s1);
        }
        int kj = jt * 64 + lane;
        if (kj > q0) s0 = -INFINITY;
        if (kj > q1) s1 = -INFINITY;

        // wave max
        float mt0 = s0, mt1 = s1;
#pragma unroll
        for (int o = 32; o > 0; o >>= 1) {
            mt0 = fmaxf(mt0, __shfl_xor(mt0, o));
            mt1 = fmaxf(mt1, __shfl_xor(mt1, o));
        }
        float mn0 = fmaxf(m0, mt0);
        float mn1 = fmaxf(m1, mt1);
        float a0 = __expf(m0 - mn0);
        float a1 = __expf(m1 - mn1);
        float p0 = __expf(s0 - mn0);
        float p1 = __expf(s1 - mn1);
        float sum0 = p0, sum1 = p1;
#pragma unroll
        for (int o = 32; o > 0; o >>= 1) {
            sum0 += __shfl_xor(sum0, o);
            sum1 += __shfl_xor(sum1, o);
        }
        l0 = l0 * a0 + sum0;
        l1 = l1 * a1 + sum1;
        m0 = mn0;
        m1 = mn1;
        ps[w][0][lane] = p0;
        ps[w][1][lane] = p1;

        // --- PV phase: lane = output dim d ---
        float acc0 = 0.f, acc1 = 0.f;
#pragma unroll
        for (int j = 0; j < 64; ++j) {
            float v = VtT[lane][j];
            acc0 = fmaf(ps[w][0][j], v, acc0);
            acc1 = fmaf(ps[w][1][j], v, acc1);
        }
        O0 = O0 * a0 + acc0;
        O1 = O1 * a1 + acc1;
    }

    y[((size_t)(b * TT + q0)) * CC + h * HD + lane] = O0 / l0;
    y[((size_t)(b * TT + q1)) * CC + h * HD + lane] = O1 / l1;
}

// ---------------------------------------------------------------------------
extern "C" void kernel_launch(void* const* d_in, const int* in_sizes, int n_in,
                              void* d_out, int out_size, void* d_ws, size_t ws_size,
                              hipStream_t stream) {
    const float* x      = (const float*)d_in[0];   // (B,T,C)
    const float* W_attn = (const float*)d_in[1];   // (C, 3C)
    const float* W_proj = (const float*)d_in[2];   // (C, C)
    float* out = (float*)d_out;                    // (B,T,C)

    float* qkv = (float*)d_ws;                          // B*T*3C floats
    float* yb  = qkv + (size_t)BB * TT * C3;            // B*T*C floats

    const int M = BB * TT;   // 8192

    // 1) qkv = x @ W_attn
    sgemm64<<<dim3(C3 / 64, M / 64), 256, 0, stream>>>(x, W_attn, qkv, M, C3, CC);

    // 2) RoPE in-place on q,k (q pre-scaled by 0.125)
    rope_kernel<<<dim3((BB * TT * (CC / 2)) / 256, 2), 256, 0, stream>>>(qkv);

    // 3) causal flash attention -> yb
    attn_kernel<<<dim3(BB * NH * (TT / 8)), 256, 0, stream>>>(qkv, yb);

    // 4) out = yb @ W_proj
    sgemm64<<<dim3(CC / 64, M / 64), 256, 0, stream>>>(yb, W_proj, out, M, CC, CC);
}

// Round 2
// 1199.953 us; speedup vs baseline: 2.4261x; 2.4261x over previous
//
#include <hip/hip_runtime.h>
#include <hip/hip_bf16.h>
#include <math.h>

// Problem constants
#define BB 4
#define TT 2048
#define CC 1024
#define NH 16
#define HD 64
#define C3 3072
#define LDK 72   // padded LDS row stride in bf16 elements (144 B, multiple of 16 B)

typedef __attribute__((ext_vector_type(8))) short bf16x8;
typedef __attribute__((ext_vector_type(4))) float f32x4;

// ---------------------------------------------------------------------------
// Tiled SGEMM (fp32 out): C[M,N] = A[M,K] @ B[K,N]
// ---------------------------------------------------------------------------
__global__ __launch_bounds__(256) void sgemm64(const float* __restrict__ A,
                                               const float* __restrict__ B,
                                               float* __restrict__ C,
                                               int M, int N, int K) {
    __shared__ __align__(16) float As[16][68];
    __shared__ __align__(16) float Bs[16][68];

    const int tid = threadIdx.x;
    const int tx = tid & 15;
    const int ty = tid >> 4;
    const int bm0 = blockIdx.y * 64;
    const int bn0 = blockIdx.x * 64;

    const int am = tid >> 2;
    const int ak = (tid & 3) * 4;
    const int bk = tid >> 4;
    const int bn = (tid & 15) * 4;

    float acc[4][4] = {};

    for (int k0 = 0; k0 < K; k0 += 16) {
        float4 av = *(const float4*)(A + (size_t)(bm0 + am) * K + k0 + ak);
        float4 bv = *(const float4*)(B + (size_t)(k0 + bk) * N + bn0 + bn);
        As[ak + 0][am] = av.x;
        As[ak + 1][am] = av.y;
        As[ak + 2][am] = av.z;
        As[ak + 3][am] = av.w;
        *(float4*)&Bs[bk][bn] = bv;
        __syncthreads();
#pragma unroll
        for (int kk = 0; kk < 16; ++kk) {
            float4 a = *(const float4*)&As[kk][ty * 4];
            float4 b = *(const float4*)&Bs[kk][tx * 4];
            acc[0][0] = fmaf(a.x, b.x, acc[0][0]);
            acc[0][1] = fmaf(a.x, b.y, acc[0][1]);
            acc[0][2] = fmaf(a.x, b.z, acc[0][2]);
            acc[0][3] = fmaf(a.x, b.w, acc[0][3]);
            acc[1][0] = fmaf(a.y, b.x, acc[1][0]);
            acc[1][1] = fmaf(a.y, b.y, acc[1][1]);
            acc[1][2] = fmaf(a.y, b.z, acc[1][2]);
            acc[1][3] = fmaf(a.y, b.w, acc[1][3]);
            acc[2][0] = fmaf(a.z, b.x, acc[2][0]);
            acc[2][1] = fmaf(a.z, b.y, acc[2][1]);
            acc[2][2] = fmaf(a.z, b.z, acc[2][2]);
            acc[2][3] = fmaf(a.z, b.w, acc[2][3]);
            acc[3][0] = fmaf(a.w, b.x, acc[3][0]);
            acc[3][1] = fmaf(a.w, b.y, acc[3][1]);
            acc[3][2] = fmaf(a.w, b.z, acc[3][2]);
            acc[3][3] = fmaf(a.w, b.w, acc[3][3]);
        }
        __syncthreads();
    }

#pragma unroll
    for (int i = 0; i < 4; ++i) {
        float4 o = make_float4(acc[i][0], acc[i][1], acc[i][2], acc[i][3]);
        *(float4*)(C + (size_t)(bm0 + ty * 4 + i) * N + bn0 + tx * 4) = o;
    }
}

// ---------------------------------------------------------------------------
// Same SGEMM but stores bf16 (for qkv, which attention consumes as bf16)
// ---------------------------------------------------------------------------
__global__ __launch_bounds__(256) void sgemm64_b16(const float* __restrict__ A,
                                                   const float* __restrict__ B,
                                                   __hip_bfloat16* __restrict__ C,
                                                   int M, int N, int K) {
    __shared__ __align__(16) float As[16][68];
    __shared__ __align__(16) float Bs[16][68];

    const int tid = threadIdx.x;
    const int tx = tid & 15;
    const int ty = tid >> 4;
    const int bm0 = blockIdx.y * 64;
    const int bn0 = blockIdx.x * 64;

    const int am = tid >> 2;
    const int ak = (tid & 3) * 4;
    const int bk = tid >> 4;
    const int bn = (tid & 15) * 4;

    float acc[4][4] = {};

    for (int k0 = 0; k0 < K; k0 += 16) {
        float4 av = *(const float4*)(A + (size_t)(bm0 + am) * K + k0 + ak);
        float4 bv = *(const float4*)(B + (size_t)(k0 + bk) * N + bn0 + bn);
        As[ak + 0][am] = av.x;
        As[ak + 1][am] = av.y;
        As[ak + 2][am] = av.z;
        As[ak + 3][am] = av.w;
        *(float4*)&Bs[bk][bn] = bv;
        __syncthreads();
#pragma unroll
        for (int kk = 0; kk < 16; ++kk) {
            float4 a = *(const float4*)&As[kk][ty * 4];
            float4 b = *(const float4*)&Bs[kk][tx * 4];
            acc[0][0] = fmaf(a.x, b.x, acc[0][0]);
            acc[0][1] = fmaf(a.x, b.y, acc[0][1]);
            acc[0][2] = fmaf(a.x, b.z, acc[0][2]);
            acc[0][3] = fmaf(a.x, b.w, acc[0][3]);
            acc[1][0] = fmaf(a.y, b.x, acc[1][0]);
            acc[1][1] = fmaf(a.y, b.y, acc[1][1]);
            acc[1][2] = fmaf(a.y, b.z, acc[1][2]);
            acc[1][3] = fmaf(a.y, b.w, acc[1][3]);
            acc[2][0] = fmaf(a.z, b.x, acc[2][0]);
            acc[2][1] = fmaf(a.z, b.y, acc[2][1]);
            acc[2][2] = fmaf(a.z, b.z, acc[2][2]);
            acc[2][3] = fmaf(a.z, b.w, acc[2][3]);
            acc[3][0] = fmaf(a.w, b.x, acc[3][0]);
            acc[3][1] = fmaf(a.w, b.y, acc[3][1]);
            acc[3][2] = fmaf(a.w, b.z, acc[3][2]);
            acc[3][3] = fmaf(a.w, b.w, acc[3][3]);
        }
        __syncthreads();
    }

#pragma unroll
    for (int i = 0; i < 4; ++i) {
        __align__(8) __hip_bfloat16 tmp[4];
        tmp[0] = __float2bfloat16(acc[i][0]);
        tmp[1] = __float2bfloat16(acc[i][1]);
        tmp[2] = __float2bfloat16(acc[i][2]);
        tmp[3] = __float2bfloat16(acc[i][3]);
        *(uint2*)(C + (size_t)(bm0 + ty * 4 + i) * N + bn0 + tx * 4) = *(uint2*)tmp;
    }
}

// ---------------------------------------------------------------------------
// RoPE (interleaved) in-place on bf16 q,k; folds 0.125 scale into q.
// ---------------------------------------------------------------------------
__global__ __launch_bounds__(256) void rope_bf16(__hip_bfloat16* __restrict__ qkvb) {
    int idx = blockIdx.x * 256 + threadIdx.x;   // pair index
    int isK = blockIdx.y;
    int c2 = idx & 511;
    int bt = idx >> 9;
    int t = bt & (TT - 1);
    int p = c2 & 31;

    float inv_freq = expf(-(float)p * (9.210340371976184f / 32.0f));
    float fr = (float)t * inv_freq;
    float s, c;
    sincosf(fr, &s, &c);

    size_t base = (size_t)bt * C3 + (size_t)isK * CC + 2 * c2;
    float x0 = __bfloat162float(qkvb[base]);
    float x1 = __bfloat162float(qkvb[base + 1]);
    float sc = isK ? 1.0f : 0.125f;
    qkvb[base]     = __float2bfloat16((x0 * c - x1 * s) * sc);
    qkvb[base + 1] = __float2bfloat16((x1 * c + x0 * s) * sc);
}

// ---------------------------------------------------------------------------
// Transpose V: qkvb[b][t][2C + h*64 + d] -> vtb[(b*16+h)*64 + d][t]
// One block per (b,h, 64-t tile).
// ---------------------------------------------------------------------------
__global__ __launch_bounds__(256) void vtranspose(const __hip_bfloat16* __restrict__ qkvb,
                                                  __hip_bfloat16* __restrict__ vtb) {
    __shared__ __align__(16) __hip_bfloat16 st[64][LDK];
    const int bh = blockIdx.x >> 5;
    const int tt = blockIdx.x & 31;
    const int b = bh >> 4;
    const int h = bh & 15;
    const int tid = threadIdx.x;
    const int row = tid >> 3;           // 0..31
    const int col8 = (tid & 7) * 8;     // 0..56

#pragma unroll
    for (int pass = 0; pass < 2; ++pass) {
        int t = pass * 32 + row;
        *(bf16x8*)(&st[t][col8]) =
            *(const bf16x8*)(qkvb + ((size_t)(b * TT + tt * 64 + t)) * C3 + 2 * CC + h * HD + col8);
    }
    __syncthreads();
#pragma unroll
    for (int pass = 0; pass < 2; ++pass) {
        int d = pass * 32 + row;
        __align__(16) __hip_bfloat16 tmp[8];
#pragma unroll
        for (int j = 0; j < 8; ++j) tmp[j] = st[col8 + j][d];
        *(bf16x8*)(vtb + ((size_t)bh * HD + d) * TT + tt * 64 + col8) = *(bf16x8*)tmp;
    }
}

// ---------------------------------------------------------------------------
// MFMA flash attention (causal). Block = 4 waves = 64 queries of one (b,h).
// Wave w owns queries q0..q0+15. K-tile/V-tile = 64 keys staged in LDS (bf16).
// S = Q K^T via mfma_f32_16x16x32_bf16 (C layout: row=quad*4+reg, col=lane&15)
// P -> LDS -> A-layout fragments -> O += P V. Online softmax per quad.
// ---------------------------------------------------------------------------
__global__ __launch_bounds__(256) void attn_mfma(const __hip_bfloat16* __restrict__ qkvb,
                                                 const __hip_bfloat16* __restrict__ vtb,
                                                 float* __restrict__ y) {
    __shared__ __align__(16) __hip_bfloat16 Ks[64 * LDK];   // [key][dim]
    __shared__ __align__(16) __hip_bfloat16 Vs[64 * LDK];   // [dim][key] (pre-transposed global)
    __shared__ __align__(16) __hip_bfloat16 Ps[4][16 * LDK]; // per-wave P [row][key]

    const int tid = threadIdx.x;
    const int w = tid >> 6;
    const int lane = tid & 63;
    const int l16 = lane & 15;
    const int quad = lane >> 4;

    const int bh = blockIdx.x >> 5;
    const int qt = 31 - (blockIdx.x & 31);   // heavy (late-query) blocks first
    const int b = bh >> 4;
    const int h = bh & 15;

    const int q0 = qt * 64 + w * 16;         // wave's first query (global t index)

    // Q A-fragments, held in registers for the whole kernel.
    // A[m=lane&15][k=quad*8+j]; q pre-scaled by 0.125 in rope.
    const size_t qrow = ((size_t)(b * TT + q0 + l16)) * C3 + h * HD;
    const bf16x8 qf0 = *(const bf16x8*)(qkvb + qrow + quad * 8);
    const bf16x8 qf1 = *(const bf16x8*)(qkvb + qrow + 32 + quad * 8);

    f32x4 O[4] = {};              // O C-frags over 4 dim-tiles
    float m_r[4], l_r[4];
#pragma unroll
    for (int r = 0; r < 4; ++r) { m_r[r] = -__builtin_inff(); l_r[r] = 0.f; }

    // staging mapping: 256 threads, 2 passes of 32 rows x (8 lanes * 8 bf16)
    const int srow = tid >> 3;
    const int scol = (tid & 7) * 8;

    for (int jt = 0; jt <= qt; ++jt) {
        __syncthreads();   // previous tile fully consumed
#pragma unroll
        for (int pass = 0; pass < 2; ++pass) {
            int r = pass * 32 + srow;
            // K[key=r][dim] from qkvb k-section
            *(bf16x8*)(Ks + r * LDK + scol) =
                *(const bf16x8*)(qkvb + ((size_t)(b * TT + jt * 64 + r)) * C3 + CC + h * HD + scol);
            // Vt[dim=r][key] from vtb
            *(bf16x8*)(Vs + r * LDK + scol) =
                *(const bf16x8*)(vtb + ((size_t)bh * HD + r) * TT + jt * 64 + scol);
        }
        __syncthreads();

        // ---- scores: S (16 queries x 64 keys) in 4 C-frags ----
        f32x4 S[4] = {};
#pragma unroll
        for (int ct = 0; ct < 4; ++ct) {
            const __hip_bfloat16* kb = Ks + (ct * 16 + l16) * LDK + quad * 8;
            bf16x8 kf0 = *(const bf16x8*)(kb);
            bf16x8 kf1 = *(const bf16x8*)(kb + 32);
            S[ct] = __builtin_amdgcn_mfma_f32_16x16x32_bf16(qf0, kf0, S[ct], 0, 0, 0);
            S[ct] = __builtin_amdgcn_mfma_f32_16x16x32_bf16(qf1, kf1, S[ct], 0, 0, 0);
        }

        // ---- causal mask (diagonal tile only; wave-uniform branch) ----
        if (jt == qt) {
#pragma unroll
            for (int ct = 0; ct < 4; ++ct) {
                int key = jt * 64 + ct * 16 + l16;
#pragma unroll
                for (int r = 0; r < 4; ++r) {
                    if (key > q0 + quad * 4 + r) S[ct][r] = -__builtin_inff();
                }
            }
        }

        // ---- online softmax (rows owned by quad: row = quad*4 + r) ----
        float alpha[4];
#pragma unroll
        for (int r = 0; r < 4; ++r) {
            float mx = fmaxf(fmaxf(S[0][r], S[1][r]), fmaxf(S[2][r], S[3][r]));
            mx = fmaxf(mx, __shfl_xor(mx, 8));
            mx = fmaxf(mx, __shfl_xor(mx, 4));
            mx = fmaxf(mx, __shfl_xor(mx, 2));
            mx = fmaxf(mx, __shfl_xor(mx, 1));
            float mnew = fmaxf(m_r[r], mx);
            alpha[r] = __expf(m_r[r] - mnew);
            m_r[r] = mnew;
            float sum = 0.f;
#pragma unroll
            for (int ct = 0; ct < 4; ++ct) {
                float p = __expf(S[ct][r] - mnew);
                S[ct][r] = p;
                sum += p;
            }
            sum += __shfl_xor(sum, 8);
            sum += __shfl_xor(sum, 4);
            sum += __shfl_xor(sum, 2);
            sum += __shfl_xor(sum, 1);
            l_r[r] = l_r[r] * alpha[r] + sum;
        }

        // ---- P -> LDS (C layout -> row-major [row][key]) ----
#pragma unroll
        for (int ct = 0; ct < 4; ++ct) {
#pragma unroll
            for (int r = 0; r < 4; ++r) {
                Ps[w][(quad * 4 + r) * LDK + ct * 16 + l16] = __float2bfloat16(S[ct][r]);
            }
        }

        // ---- rescale O, then O += P V ----
#pragma unroll
        for (int ct = 0; ct < 4; ++ct) {
#pragma unroll
            for (int r = 0; r < 4; ++r) O[ct][r] *= alpha[r];
        }
        const __hip_bfloat16* pb = Ps[w] + l16 * LDK + quad * 8;
        bf16x8 pf0 = *(const bf16x8*)(pb);
        bf16x8 pf1 = *(const bf16x8*)(pb + 32);
#pragma unroll
        for (int ct = 0; ct < 4; ++ct) {
            const __hip_bfloat16* vb = Vs + (ct * 16 + l16) * LDK + quad * 8;
            bf16x8 vf0 = *(const bf16x8*)(vb);
            bf16x8 vf1 = *(const bf16x8*)(vb + 32);
            O[ct] = __builtin_amdgcn_mfma_f32_16x16x32_bf16(pf0, vf0, O[ct], 0, 0, 0);
            O[ct] = __builtin_amdgcn_mfma_f32_16x16x32_bf16(pf1, vf1, O[ct], 0, 0, 0);
        }
    }

    // ---- epilogue: normalize and store (C layout: row=quad*4+r, col=l16) ----
    float inv[4];
#pragma unroll
    for (int r = 0; r < 4; ++r) inv[r] = 1.0f / l_r[r];
#pragma unroll
    for (int ct = 0; ct < 4; ++ct) {
#pragma unroll
        for (int r = 0; r < 4; ++r) {
            y[((size_t)(b * TT + q0 + quad * 4 + r)) * CC + h * HD + ct * 16 + l16] = O[ct][r] * inv[r];
        }
    }
}

// ---------------------------------------------------------------------------
extern "C" void kernel_launch(void* const* d_in, const int* in_sizes, int n_in,
                              void* d_out, int out_size, void* d_ws, size_t ws_size,
                              hipStream_t stream) {
    const float* x      = (const float*)d_in[0];   // (B,T,C)
    const float* W_attn = (const float*)d_in[1];   // (C, 3C)
    const float* W_proj = (const float*)d_in[2];   // (C, C)
    float* out = (float*)d_out;                    // (B,T,C)

    // workspace layout (96 MB total)
    __hip_bfloat16* qkvb = (__hip_bfloat16*)d_ws;                    // B*T*3C bf16 = 48 MB
    __hip_bfloat16* vtb  = qkvb + (size_t)BB * TT * C3;              // B*H*64*T bf16 = 16 MB
    float* yb = (float*)(vtb + (size_t)BB * NH * HD * TT);           // B*T*C fp32 = 32 MB

    const int M = BB * TT;   // 8192

    // 1) qkv = x @ W_attn  (bf16 out)
    sgemm64_b16<<<dim3(C3 / 64, M / 64), 256, 0, stream>>>(x, W_attn, qkvb, M, C3, CC);

    // 2) RoPE in-place on bf16 q,k (q pre-scaled by 0.125)
    rope_bf16<<<dim3((BB * TT * (CC / 2)) / 256, 2), 256, 0, stream>>>(qkvb);

    // 3) transpose V into vtb
    vtranspose<<<dim3(BB * NH * (TT / 64)), 256, 0, stream>>>(qkvb, vtb);

    // 4) MFMA flash attention -> yb
    attn_mfma<<<dim3(BB * NH * (TT / 64)), 256, 0, stream>>>(qkvb, vtb, yb);

    // 5) out = yb @ W_proj
    sgemm64<<<dim3(CC / 64, M / 64), 256, 0, stream>>>(yb, W_proj, out, M, CC, CC);
}

// Round 3
// 472.735 us; speedup vs baseline: 6.1582x; 2.5383x over previous
//
#include <hip/hip_runtime.h>
#include <hip/hip_bf16.h>
#include <math.h>

// Problem constants
#define BB 4
#define TT 2048
#define CC 1024
#define NH 16
#define HD 64
#define C3 3072
#define LDK 72   // padded LDS row stride in bf16 elements (144 B)

typedef __attribute__((ext_vector_type(8))) short bf16x8;
typedef __attribute__((ext_vector_type(4))) float f32x4;

// async global->LDS, 16 B per lane; LDS dest = wave-uniform base + lane*16
__device__ __forceinline__ void gload_lds16(const __hip_bfloat16* g, __hip_bfloat16* s) {
    __builtin_amdgcn_global_load_lds((const __attribute__((address_space(1))) void*)g,
                                     (__attribute__((address_space(3))) void*)s, 16, 0, 0);
}

// ---------------------------------------------------------------------------
// cast fp32 -> bf16, 8 elements/thread
// ---------------------------------------------------------------------------
__global__ __launch_bounds__(256) void cast_bf16x8(const float* __restrict__ X,
                                                   __hip_bfloat16* __restrict__ Y) {
    size_t i = ((size_t)blockIdx.x * 256 + threadIdx.x) * 8;
    float4 a = *(const float4*)(X + i);
    float4 b = *(const float4*)(X + i + 4);
    __align__(16) __hip_bfloat16 tmp[8];
    tmp[0] = __float2bfloat16(a.x);
    tmp[1] = __float2bfloat16(a.y);
    tmp[2] = __float2bfloat16(a.z);
    tmp[3] = __float2bfloat16(a.w);
    tmp[4] = __float2bfloat16(b.x);
    tmp[5] = __float2bfloat16(b.y);
    tmp[6] = __float2bfloat16(b.z);
    tmp[7] = __float2bfloat16(b.w);
    *(bf16x8*)(Y + i) = *(bf16x8*)tmp;
}

// ---------------------------------------------------------------------------
// W[K][N] fp32  ->  Wt[N][K] bf16   (64x64 tiles via LDS)
// ---------------------------------------------------------------------------
__global__ __launch_bounds__(256) void wtrans(const float* __restrict__ W,
                                              __hip_bfloat16* __restrict__ Wt,
                                              int K, int N) {
    __shared__ float st[64][65];
    const int n0 = blockIdx.x * 64;
    const int k0 = blockIdx.y * 64;
    const int tid = threadIdx.x;
    const int r = tid >> 4;          // 0..15
    const int c4 = (tid & 15) * 4;
#pragma unroll
    for (int p = 0; p < 4; ++p) {
        int k = p * 16 + r;
        float4 v = *(const float4*)(W + (size_t)(k0 + k) * N + n0 + c4);
        st[c4 + 0][k] = v.x;
        st[c4 + 1][k] = v.y;
        st[c4 + 2][k] = v.z;
        st[c4 + 3][k] = v.w;
    }
    __syncthreads();
    const int rr = tid >> 3;         // 0..31
    const int cc = (tid & 7) * 8;
#pragma unroll
    for (int p = 0; p < 2; ++p) {
        int n = p * 32 + rr;
        __align__(16) __hip_bfloat16 tmp[8];
#pragma unroll
        for (int j = 0; j < 8; ++j) tmp[j] = __float2bfloat16(st[n][cc + j]);
        *(bf16x8*)(Wt + (size_t)(n0 + n) * K + k0 + cc) = *(bf16x8*)tmp;
    }
}

// ---------------------------------------------------------------------------
// MFMA GEMM (m97 structure): C[M,N] = A[M,K] @ Bt[N,K]^T, bf16 in, fp32 acc.
// 256 thr = 2x2 waves, 128x128 tile, BK=32, global_load_lds width 16.
// ---------------------------------------------------------------------------
#define GEMM_BODY(STORE)                                                              \
    __shared__ __align__(16) __hip_bfloat16 As[128 * 32];                             \
    __shared__ __align__(16) __hip_bfloat16 Bs[128 * 32];                             \
    const int tid = threadIdx.x;                                                      \
    const int w = tid >> 6;                                                           \
    const int lane = tid & 63;                                                        \
    const int l16 = lane & 15;                                                        \
    const int quad = lane >> 4;                                                       \
    const int wm = w >> 1;                                                            \
    const int wn = w & 1;                                                             \
    const int bm0 = blockIdx.y * 128;                                                 \
    const int bn0 = blockIdx.x * 128;                                                 \
    const int lrow = tid >> 2;                                                        \
    const int lcol = (tid & 3) * 8;                                                   \
    const __hip_bfloat16* Ag = A + (size_t)(bm0 + lrow) * K + lcol;                   \
    const __hip_bfloat16* Bg = Bt + (size_t)(bn0 + lrow) * K + lcol;                  \
    __hip_bfloat16* Asw0 = As + w * 512;                                              \
    __hip_bfloat16* Asw1 = As + 2048 + w * 512;                                       \
    __hip_bfloat16* Bsw0 = Bs + w * 512;                                              \
    __hip_bfloat16* Bsw1 = Bs + 2048 + w * 512;                                       \
    const size_t rowK64 = (size_t)64 * K;                                             \
    f32x4 acc[4][4] = {};                                                             \
    for (int k0 = 0; k0 < K; k0 += 32) {                                              \
        __syncthreads();                                                              \
        gload_lds16(Ag + k0, Asw0);                                                   \
        gload_lds16(Ag + rowK64 + k0, Asw1);                                          \
        gload_lds16(Bg + k0, Bsw0);                                                   \
        gload_lds16(Bg + rowK64 + k0, Bsw1);                                          \
        __syncthreads();                                                              \
        bf16x8 af[4], bfv[4];                                                         \
        _Pragma("unroll")                                                             \
        for (int t = 0; t < 4; ++t) {                                                 \
            af[t] = *(const bf16x8*)(As + (wm * 64 + t * 16 + l16) * 32 + quad * 8);  \
            bfv[t] = *(const bf16x8*)(Bs + (wn * 64 + t * 16 + l16) * 32 + quad * 8); \
        }                                                                             \
        _Pragma("unroll")                                                             \
        for (int mt = 0; mt < 4; ++mt)                                                \
            _Pragma("unroll")                                                         \
            for (int nt = 0; nt < 4; ++nt)                                            \
                acc[mt][nt] = __builtin_amdgcn_mfma_f32_16x16x32_bf16(                \
                    af[mt], bfv[nt], acc[mt][nt], 0, 0, 0);                           \
    }                                                                                 \
    _Pragma("unroll")                                                                 \
    for (int mt = 0; mt < 4; ++mt) {                                                  \
        int row = bm0 + wm * 64 + mt * 16 + quad * 4;                                 \
        _Pragma("unroll")                                                             \
        for (int nt = 0; nt < 4; ++nt) {                                              \
            int col = bn0 + wn * 64 + nt * 16 + l16;                                  \
            _Pragma("unroll")                                                         \
            for (int r = 0; r < 4; ++r) STORE;                                        \
        }                                                                             \
    }

__global__ __launch_bounds__(256) void gemm_bt_b16(const __hip_bfloat16* __restrict__ A,
                                                   const __hip_bfloat16* __restrict__ Bt,
                                                   __hip_bfloat16* __restrict__ C,
                                                   int M, int N, int K) {
    GEMM_BODY(C[(size_t)(row + r) * N + col] = __float2bfloat16(acc[mt][nt][r]))
}

__global__ __launch_bounds__(256) void gemm_bt_f32(const __hip_bfloat16* __restrict__ A,
                                                   const __hip_bfloat16* __restrict__ Bt,
                                                   float* __restrict__ C,
                                                   int M, int N, int K) {
    GEMM_BODY(C[(size_t)(row + r) * N + col] = acc[mt][nt][r])
}

// ---------------------------------------------------------------------------
// RoPE (interleaved) in-place on bf16 q,k; folds 0.125 scale into q.
// ---------------------------------------------------------------------------
__global__ __launch_bounds__(256) void rope_bf16(__hip_bfloat16* __restrict__ qkvb) {
    int idx = blockIdx.x * 256 + threadIdx.x;   // pair index
    int isK = blockIdx.y;
    int c2 = idx & 511;
    int bt = idx >> 9;
    int t = bt & (TT - 1);
    int p = c2 & 31;

    float inv_freq = expf(-(float)p * (9.210340371976184f / 32.0f));
    float fr = (float)t * inv_freq;
    float s, c;
    sincosf(fr, &s, &c);

    size_t base = (size_t)bt * C3 + (size_t)isK * CC + 2 * c2;
    float x0 = __bfloat162float(qkvb[base]);
    float x1 = __bfloat162float(qkvb[base + 1]);
    float sc = isK ? 1.0f : 0.125f;
    qkvb[base]     = __float2bfloat16((x0 * c - x1 * s) * sc);
    qkvb[base + 1] = __float2bfloat16((x1 * c + x0 * s) * sc);
}

// ---------------------------------------------------------------------------
// Transpose V: qkvb[b][t][2C + h*64 + d] -> vtb[(b*16+h)*64 + d][t]
// ---------------------------------------------------------------------------
__global__ __launch_bounds__(256) void vtranspose(const __hip_bfloat16* __restrict__ qkvb,
                                                  __hip_bfloat16* __restrict__ vtb) {
    __shared__ __align__(16) __hip_bfloat16 st[64][LDK];
    const int bh = blockIdx.x >> 5;
    const int tt = blockIdx.x & 31;
    const int b = bh >> 4;
    const int h = bh & 15;
    const int tid = threadIdx.x;
    const int row = tid >> 3;           // 0..31
    const int col8 = (tid & 7) * 8;     // 0..56

#pragma unroll
    for (int pass = 0; pass < 2; ++pass) {
        int t = pass * 32 + row;
        *(bf16x8*)(&st[t][col8]) =
            *(const bf16x8*)(qkvb + ((size_t)(b * TT + tt * 64 + t)) * C3 + 2 * CC + h * HD + col8);
    }
    __syncthreads();
#pragma unroll
    for (int pass = 0; pass < 2; ++pass) {
        int d = pass * 32 + row;
        __align__(16) __hip_bfloat16 tmp[8];
#pragma unroll
        for (int j = 0; j < 8; ++j) tmp[j] = st[col8 + j][d];
        *(bf16x8*)(vtb + ((size_t)bh * HD + d) * TT + tt * 64 + col8) = *(bf16x8*)tmp;
    }
}

// ---------------------------------------------------------------------------
// MFMA flash attention (causal). Block = 4 waves = 64 queries of one (b,h).
// Output bf16 (feeds MFMA out-proj GEMM).
// ---------------------------------------------------------------------------
__global__ __launch_bounds__(256) void attn_mfma(const __hip_bfloat16* __restrict__ qkvb,
                                                 const __hip_bfloat16* __restrict__ vtb,
                                                 __hip_bfloat16* __restrict__ y) {
    __shared__ __align__(16) __hip_bfloat16 Ks[64 * LDK];    // [key][dim]
    __shared__ __align__(16) __hip_bfloat16 Vs[64 * LDK];    // [dim][key]
    __shared__ __align__(16) __hip_bfloat16 Ps[4][16 * LDK]; // per-wave P [row][key]

    const int tid = threadIdx.x;
    const int w = tid >> 6;
    const int lane = tid & 63;
    const int l16 = lane & 15;
    const int quad = lane >> 4;

    const int bh = blockIdx.x >> 5;
    const int qt = 31 - (blockIdx.x & 31);   // heavy (late-query) blocks first
    const int b = bh >> 4;
    const int h = bh & 15;

    const int q0 = qt * 64 + w * 16;

    const size_t qrow = ((size_t)(b * TT + q0 + l16)) * C3 + h * HD;
    const bf16x8 qf0 = *(const bf16x8*)(qkvb + qrow + quad * 8);
    const bf16x8 qf1 = *(const bf16x8*)(qkvb + qrow + 32 + quad * 8);

    f32x4 O[4] = {};
    float m_r[4], l_r[4];
#pragma unroll
    for (int r = 0; r < 4; ++r) { m_r[r] = -__builtin_inff(); l_r[r] = 0.f; }

    const int srow = tid >> 3;
    const int scol = (tid & 7) * 8;

    for (int jt = 0; jt <= qt; ++jt) {
        __syncthreads();
#pragma unroll
        for (int pass = 0; pass < 2; ++pass) {
            int r = pass * 32 + srow;
            *(bf16x8*)(Ks + r * LDK + scol) =
                *(const bf16x8*)(qkvb + ((size_t)(b * TT + jt * 64 + r)) * C3 + CC + h * HD + scol);
            *(bf16x8*)(Vs + r * LDK + scol) =
                *(const bf16x8*)(vtb + ((size_t)bh * HD + r) * TT + jt * 64 + scol);
        }
        __syncthreads();

        // ---- scores ----
        f32x4 S[4] = {};
#pragma unroll
        for (int ct = 0; ct < 4; ++ct) {
            const __hip_bfloat16* kb = Ks + (ct * 16 + l16) * LDK + quad * 8;
            bf16x8 kf0 = *(const bf16x8*)(kb);
            bf16x8 kf1 = *(const bf16x8*)(kb + 32);
            S[ct] = __builtin_amdgcn_mfma_f32_16x16x32_bf16(qf0, kf0, S[ct], 0, 0, 0);
            S[ct] = __builtin_amdgcn_mfma_f32_16x16x32_bf16(qf1, kf1, S[ct], 0, 0, 0);
        }

        if (jt == qt) {
#pragma unroll
            for (int ct = 0; ct < 4; ++ct) {
                int key = jt * 64 + ct * 16 + l16;
#pragma unroll
                for (int r = 0; r < 4; ++r) {
                    if (key > q0 + quad * 4 + r) S[ct][r] = -__builtin_inff();
                }
            }
        }

        // ---- online softmax ----
        float alpha[4];
#pragma unroll
        for (int r = 0; r < 4; ++r) {
            float mx = fmaxf(fmaxf(S[0][r], S[1][r]), fmaxf(S[2][r], S[3][r]));
            mx = fmaxf(mx, __shfl_xor(mx, 8));
            mx = fmaxf(mx, __shfl_xor(mx, 4));
            mx = fmaxf(mx, __shfl_xor(mx, 2));
            mx = fmaxf(mx, __shfl_xor(mx, 1));
            float mnew = fmaxf(m_r[r], mx);
            alpha[r] = __expf(m_r[r] - mnew);
            m_r[r] = mnew;
            float sum = 0.f;
#pragma unroll
            for (int ct = 0; ct < 4; ++ct) {
                float p = __expf(S[ct][r] - mnew);
                S[ct][r] = p;
                sum += p;
            }
            sum += __shfl_xor(sum, 8);
            sum += __shfl_xor(sum, 4);
            sum += __shfl_xor(sum, 2);
            sum += __shfl_xor(sum, 1);
            l_r[r] = l_r[r] * alpha[r] + sum;
        }

        // ---- P -> LDS ----
#pragma unroll
        for (int ct = 0; ct < 4; ++ct) {
#pragma unroll
            for (int r = 0; r < 4; ++r) {
                Ps[w][(quad * 4 + r) * LDK + ct * 16 + l16] = __float2bfloat16(S[ct][r]);
            }
        }

        // ---- O rescale + O += P V ----
#pragma unroll
        for (int ct = 0; ct < 4; ++ct) {
#pragma unroll
            for (int r = 0; r < 4; ++r) O[ct][r] *= alpha[r];
        }
        const __hip_bfloat16* pb = Ps[w] + l16 * LDK + quad * 8;
        bf16x8 pf0 = *(const bf16x8*)(pb);
        bf16x8 pf1 = *(const bf16x8*)(pb + 32);
#pragma unroll
        for (int ct = 0; ct < 4; ++ct) {
            const __hip_bfloat16* vb = Vs + (ct * 16 + l16) * LDK + quad * 8;
            bf16x8 vf0 = *(const bf16x8*)(vb);
            bf16x8 vf1 = *(const bf16x8*)(vb + 32);
            O[ct] = __builtin_amdgcn_mfma_f32_16x16x32_bf16(pf0, vf0, O[ct], 0, 0, 0);
            O[ct] = __builtin_amdgcn_mfma_f32_16x16x32_bf16(pf1, vf1, O[ct], 0, 0, 0);
        }
    }

    float inv[4];
#pragma unroll
    for (int r = 0; r < 4; ++r) inv[r] = 1.0f / l_r[r];
#pragma unroll
    for (int ct = 0; ct < 4; ++ct) {
#pragma unroll
        for (int r = 0; r < 4; ++r) {
            y[((size_t)(b * TT + q0 + quad * 4 + r)) * CC + h * HD + ct * 16 + l16] =
                __float2bfloat16(O[ct][r] * inv[r]);
        }
    }
}

// ---------------------------------------------------------------------------
extern "C" void kernel_launch(void* const* d_in, const int* in_sizes, int n_in,
                              void* d_out, int out_size, void* d_ws, size_t ws_size,
                              hipStream_t stream) {
    const float* x      = (const float*)d_in[0];   // (B,T,C)
    const float* W_attn = (const float*)d_in[1];   // (C, 3C)
    const float* W_proj = (const float*)d_in[2];   // (C, C)
    float* out = (float*)d_out;                    // (B,T,C)

    const size_t NBT = (size_t)BB * TT;            // 8192
    // workspace layout (~92 MB)
    __hip_bfloat16* xb   = (__hip_bfloat16*)d_ws;           // B*T*C    (reused as yb)
    __hip_bfloat16* qkvb = xb + NBT * CC;                   // B*T*3C
    __hip_bfloat16* vtb  = qkvb + NBT * C3;                 // B*H*64*T
    __hip_bfloat16* Wab  = vtb + NBT * CC;                  // 3C*C  [N][K]
    __hip_bfloat16* Wpb  = Wab + (size_t)CC * C3;           // C*C   [N][K]
    __hip_bfloat16* yb   = xb;                              // reuse after qkv GEMM

    const int M = BB * TT;   // 8192

    // prep: casts + weight transposes
    cast_bf16x8<<<dim3((int)(NBT * CC / 2048)), 256, 0, stream>>>(x, xb);
    wtrans<<<dim3(C3 / 64, CC / 64), 256, 0, stream>>>(W_attn, Wab, CC, C3);
    wtrans<<<dim3(CC / 64, CC / 64), 256, 0, stream>>>(W_proj, Wpb, CC, CC);

    // 1) qkv = x @ W_attn  (MFMA, bf16 out)
    gemm_bt_b16<<<dim3(C3 / 128, M / 128), 256, 0, stream>>>(xb, Wab, qkvb, M, C3, CC);

    // 2) RoPE in-place on bf16 q,k (q pre-scaled by 0.125)
    rope_bf16<<<dim3((BB * TT * (CC / 2)) / 256, 2), 256, 0, stream>>>(qkvb);

    // 3) transpose V
    vtranspose<<<dim3(BB * NH * (TT / 64)), 256, 0, stream>>>(qkvb, vtb);

    // 4) MFMA flash attention -> yb (bf16)
    attn_mfma<<<dim3(BB * NH * (TT / 64)), 256, 0, stream>>>(qkvb, vtb, yb);

    // 5) out = yb @ W_proj  (MFMA, fp32 out)
    gemm_bt_f32<<<dim3(CC / 128, M / 128), 256, 0, stream>>>(yb, Wpb, out, M, CC, CC);
}

// Round 4
// 378.028 us; speedup vs baseline: 7.7011x; 1.2505x over previous
//
#include <hip/hip_runtime.h>
#include <hip/hip_bf16.h>
#include <math.h>

// Problem constants
#define BB 4
#define TT 2048
#define CC 1024
#define NH 16
#define HD 64
#define C3 3072
#define LDK 72   // padded LDS row stride in bf16 elements (144 B) - vtranspose only

typedef __attribute__((ext_vector_type(8))) short bf16x8;
typedef __attribute__((ext_vector_type(4))) float f32x4;

// async global->LDS, 16 B per lane; LDS dest = wave-uniform base + lane*16
__device__ __forceinline__ void gload_lds16(const __hip_bfloat16* g, __hip_bfloat16* s) {
    __builtin_amdgcn_global_load_lds((const __attribute__((address_space(1))) void*)g,
                                     (__attribute__((address_space(3))) void*)s, 16, 0, 0);
}

// ---------------------------------------------------------------------------
// cast fp32 -> bf16, 8 elements/thread
// ---------------------------------------------------------------------------
__global__ __launch_bounds__(256) void cast_bf16x8(const float* __restrict__ X,
                                                   __hip_bfloat16* __restrict__ Y) {
    size_t i = ((size_t)blockIdx.x * 256 + threadIdx.x) * 8;
    float4 a = *(const float4*)(X + i);
    float4 b = *(const float4*)(X + i + 4);
    __align__(16) __hip_bfloat16 tmp[8];
    tmp[0] = __float2bfloat16(a.x);
    tmp[1] = __float2bfloat16(a.y);
    tmp[2] = __float2bfloat16(a.z);
    tmp[3] = __float2bfloat16(a.w);
    tmp[4] = __float2bfloat16(b.x);
    tmp[5] = __float2bfloat16(b.y);
    tmp[6] = __float2bfloat16(b.z);
    tmp[7] = __float2bfloat16(b.w);
    *(bf16x8*)(Y + i) = *(bf16x8*)tmp;
}

// ---------------------------------------------------------------------------
// W[K][N] fp32  ->  Wt[N][K] bf16   (64x64 tiles via LDS)
// ---------------------------------------------------------------------------
__global__ __launch_bounds__(256) void wtrans(const float* __restrict__ W,
                                              __hip_bfloat16* __restrict__ Wt,
                                              int K, int N) {
    __shared__ float st[64][65];
    const int n0 = blockIdx.x * 64;
    const int k0 = blockIdx.y * 64;
    const int tid = threadIdx.x;
    const int r = tid >> 4;          // 0..15
    const int c4 = (tid & 15) * 4;
#pragma unroll
    for (int p = 0; p < 4; ++p) {
        int k = p * 16 + r;
        float4 v = *(const float4*)(W + (size_t)(k0 + k) * N + n0 + c4);
        st[c4 + 0][k] = v.x;
        st[c4 + 1][k] = v.y;
        st[c4 + 2][k] = v.z;
        st[c4 + 3][k] = v.w;
    }
    __syncthreads();
    const int rr = tid >> 3;         // 0..31
    const int cc = (tid & 7) * 8;
#pragma unroll
    for (int p = 0; p < 2; ++p) {
        int n = p * 32 + rr;
        __align__(16) __hip_bfloat16 tmp[8];
#pragma unroll
        for (int j = 0; j < 8; ++j) tmp[j] = __float2bfloat16(st[n][cc + j]);
        *(bf16x8*)(Wt + (size_t)(n0 + n) * K + k0 + cc) = *(bf16x8*)tmp;
    }
}

// ---------------------------------------------------------------------------
// MFMA GEMM (m97 structure): C[M,N] = A[M,K] @ Bt[N,K]^T, bf16 in, fp32 acc.
// ---------------------------------------------------------------------------
#define GEMM_BODY(STORE)                                                              \
    __shared__ __align__(16) __hip_bfloat16 As[128 * 32];                             \
    __shared__ __align__(16) __hip_bfloat16 Bs[128 * 32];                             \
    const int tid = threadIdx.x;                                                      \
    const int w = tid >> 6;                                                           \
    const int lane = tid & 63;                                                        \
    const int l16 = lane & 15;                                                        \
    const int quad = lane >> 4;                                                       \
    const int wm = w >> 1;                                                            \
    const int wn = w & 1;                                                             \
    const int bm0 = blockIdx.y * 128;                                                 \
    const int bn0 = blockIdx.x * 128;                                                 \
    const int lrow = tid >> 2;                                                        \
    const int lcol = (tid & 3) * 8;                                                   \
    const __hip_bfloat16* Ag = A + (size_t)(bm0 + lrow) * K + lcol;                   \
    const __hip_bfloat16* Bg = Bt + (size_t)(bn0 + lrow) * K + lcol;                  \
    __hip_bfloat16* Asw0 = As + w * 512;                                              \
    __hip_bfloat16* Asw1 = As + 2048 + w * 512;                                       \
    __hip_bfloat16* Bsw0 = Bs + w * 512;                                              \
    __hip_bfloat16* Bsw1 = Bs + 2048 + w * 512;                                       \
    const size_t rowK64 = (size_t)64 * K;                                             \
    f32x4 acc[4][4] = {};                                                             \
    for (int k0 = 0; k0 < K; k0 += 32) {                                              \
        __syncthreads();                                                              \
        gload_lds16(Ag + k0, Asw0);                                                   \
        gload_lds16(Ag + rowK64 + k0, Asw1);                                          \
        gload_lds16(Bg + k0, Bsw0);                                                   \
        gload_lds16(Bg + rowK64 + k0, Bsw1);                                          \
        __syncthreads();                                                              \
        bf16x8 af[4], bfv[4];                                                         \
        _Pragma("unroll")                                                             \
        for (int t = 0; t < 4; ++t) {                                                 \
            af[t] = *(const bf16x8*)(As + (wm * 64 + t * 16 + l16) * 32 + quad * 8);  \
            bfv[t] = *(const bf16x8*)(Bs + (wn * 64 + t * 16 + l16) * 32 + quad * 8); \
        }                                                                             \
        _Pragma("unroll")                                                             \
        for (int mt = 0; mt < 4; ++mt)                                                \
            _Pragma("unroll")                                                         \
            for (int nt = 0; nt < 4; ++nt)                                            \
                acc[mt][nt] = __builtin_amdgcn_mfma_f32_16x16x32_bf16(                \
                    af[mt], bfv[nt], acc[mt][nt], 0, 0, 0);                           \
    }                                                                                 \
    _Pragma("unroll")                                                                 \
    for (int mt = 0; mt < 4; ++mt) {                                                  \
        int row = bm0 + wm * 64 + mt * 16 + quad * 4;                                 \
        _Pragma("unroll")                                                             \
        for (int nt = 0; nt < 4; ++nt) {                                              \
            int col = bn0 + wn * 64 + nt * 16 + l16;                                  \
            _Pragma("unroll")                                                         \
            for (int r = 0; r < 4; ++r) STORE;                                        \
        }                                                                             \
    }

__global__ __launch_bounds__(256) void gemm_bt_b16(const __hip_bfloat16* __restrict__ A,
                                                   const __hip_bfloat16* __restrict__ Bt,
                                                   __hip_bfloat16* __restrict__ C,
                                                   int M, int N, int K) {
    GEMM_BODY(C[(size_t)(row + r) * N + col] = __float2bfloat16(acc[mt][nt][r]))
}

__global__ __launch_bounds__(256) void gemm_bt_f32(const __hip_bfloat16* __restrict__ A,
                                                   const __hip_bfloat16* __restrict__ Bt,
                                                   float* __restrict__ C,
                                                   int M, int N, int K) {
    GEMM_BODY(C[(size_t)(row + r) * N + col] = acc[mt][nt][r])
}

// ---------------------------------------------------------------------------
// RoPE (interleaved) in-place on bf16 q,k; folds 0.125 scale into q.
// ---------------------------------------------------------------------------
__global__ __launch_bounds__(256) void rope_bf16(__hip_bfloat16* __restrict__ qkvb) {
    int idx = blockIdx.x * 256 + threadIdx.x;   // pair index
    int isK = blockIdx.y;
    int c2 = idx & 511;
    int bt = idx >> 9;
    int t = bt & (TT - 1);
    int p = c2 & 31;

    float inv_freq = expf(-(float)p * (9.210340371976184f / 32.0f));
    float fr = (float)t * inv_freq;
    float s, c;
    sincosf(fr, &s, &c);

    size_t base = (size_t)bt * C3 + (size_t)isK * CC + 2 * c2;
    float x0 = __bfloat162float(qkvb[base]);
    float x1 = __bfloat162float(qkvb[base + 1]);
    float sc = isK ? 1.0f : 0.125f;
    qkvb[base]     = __float2bfloat16((x0 * c - x1 * s) * sc);
    qkvb[base + 1] = __float2bfloat16((x1 * c + x0 * s) * sc);
}

// ---------------------------------------------------------------------------
// Transpose V: qkvb[b][t][2C + h*64 + d] -> vtb[(b*16+h)*64 + d][t]
// ---------------------------------------------------------------------------
__global__ __launch_bounds__(256) void vtranspose(const __hip_bfloat16* __restrict__ qkvb,
                                                  __hip_bfloat16* __restrict__ vtb) {
    __shared__ __align__(16) __hip_bfloat16 st[64][LDK];
    const int bh = blockIdx.x >> 5;
    const int tt = blockIdx.x & 31;
    const int b = bh >> 4;
    const int h = bh & 15;
    const int tid = threadIdx.x;
    const int row = tid >> 3;           // 0..31
    const int col8 = (tid & 7) * 8;     // 0..56

#pragma unroll
    for (int pass = 0; pass < 2; ++pass) {
        int t = pass * 32 + row;
        *(bf16x8*)(&st[t][col8]) =
            *(const bf16x8*)(qkvb + ((size_t)(b * TT + tt * 64 + t)) * C3 + 2 * CC + h * HD + col8);
    }
    __syncthreads();
#pragma unroll
    for (int pass = 0; pass < 2; ++pass) {
        int d = pass * 32 + row;
        __align__(16) __hip_bfloat16 tmp[8];
#pragma unroll
        for (int j = 0; j < 8; ++j) tmp[j] = st[col8 + j][d];
        *(bf16x8*)(vtb + ((size_t)bh * HD + d) * TT + tt * 64 + col8) = *(bf16x8*)tmp;
    }
}

// ---------------------------------------------------------------------------
// MFMA flash attention v2 (causal), S^T formulation.
// Block = 4 waves * 32 queries = 128 queries of one (b,h).
// K/V tiles (64 keys) XOR-swizzled in LDS, staged via global_load_lds,
// double-buffered, 1 barrier per tile.
// S^T = K*Q^T: C-layout row=key=quad*4+r, col=query=l16 -> softmax per lane
// column with 2 shuffles; P written row-major [query][key] with ds_write_b64;
// O = P*V^T via A=P (b128 reads), B=V^T frags.
// ---------------------------------------------------------------------------
__global__ __launch_bounds__(256) void attn_mfma2(const __hip_bfloat16* __restrict__ qkvb,
                                                  const __hip_bfloat16* __restrict__ vtb,
                                                  __hip_bfloat16* __restrict__ y) {
    __shared__ __align__(16) __hip_bfloat16 Kb[2][64 * 64];   // [key][dim], XOR-swizzled 16B chunks
    __shared__ __align__(16) __hip_bfloat16 Vb[2][64 * 64];   // [dim][key], XOR-swizzled
    __shared__ __align__(16) __hip_bfloat16 Ps[4][2][16 * 72]; // [wave][qtile][query][key], pad 72

    const int tid = threadIdx.x;
    const int w = tid >> 6;
    const int lane = tid & 63;
    const int l16 = lane & 15;
    const int quad = lane >> 4;
    const int swz = l16 & 7;                 // row-XOR for frag reads

    const int bh = blockIdx.x >> 4;
    const int qblk = 15 - (blockIdx.x & 15); // heavy blocks first
    const int b = bh >> 4;
    const int h = bh & 15;
    const int qb = qblk * 128;
    const int jtmax = 2 * qblk + 1;

    const int qn0 = qb + w * 32;             // wave's qtile bases
    const int qn1 = qn0 + 16;

    // Q B-frags (B[k=dim][n=query]): held in registers all kernel
    bf16x8 qf[2][2];
#pragma unroll
    for (int qt = 0; qt < 2; ++qt) {
        const __hip_bfloat16* qp = qkvb + (size_t)(b * TT + qn0 + qt * 16 + l16) * C3 + h * HD;
        qf[qt][0] = *(const bf16x8*)(qp + quad * 8);
        qf[qt][1] = *(const bf16x8*)(qp + 32 + quad * 8);
    }

    // staging mapping: lane -> (row-in-8, phys chunk); logical chunk = phys ^ (row&7)
    const int sr = (lane >> 3) & 7;
    const int sc = lane & 7;
    const int klog = ((sc ^ sr) * 8);        // bf16 offset within 64-elem row

    f32x4 O[2][4] = {};                      // [qtile][dim-tile], C-layout row=query,col=dim
    float m_q[2] = {-__builtin_inff(), -__builtin_inff()};
    float l_q[2] = {0.f, 0.f};

    // prologue: stage tile 0 into buffer 0
    {
        const int jt = 0;
#pragma unroll
        for (int half = 0; half < 2; ++half) {
            int kr = w * 16 + half * 8 + sr;
            gload_lds16(qkvb + (size_t)(b * TT + jt * 64 + kr) * C3 + CC + h * HD + klog,
                        Kb[0] + (w * 16 + half * 8) * 64);
            gload_lds16(vtb + ((size_t)bh * HD + kr) * TT + jt * 64 + klog,
                        Vb[0] + (w * 16 + half * 8) * 64);
        }
    }

    for (int jt = 0; jt <= jtmax; ++jt) {
        const int p = jt & 1;
        __syncthreads();   // tile jt ready (vmcnt drained); buffer p^1 free

        if (jt < jtmax) {  // prefetch tile jt+1 (async, lands before next barrier)
            const int jn = jt + 1;
#pragma unroll
            for (int half = 0; half < 2; ++half) {
                int kr = w * 16 + half * 8 + sr;
                gload_lds16(qkvb + (size_t)(b * TT + jn * 64 + kr) * C3 + CC + h * HD + klog,
                            Kb[p ^ 1] + (w * 16 + half * 8) * 64);
                gload_lds16(vtb + ((size_t)bh * HD + kr) * TT + jn * 64 + klog,
                            Vb[p ^ 1] + (w * 16 + half * 8) * 64);
            }
        }

        const bool sk0 = (jt * 64 > qn0 + 15);   // qtile fully masked
        const bool sk1 = (jt * 64 > qn1 + 15);   // sk1 implies sk0
        float a_q[2] = {1.f, 1.f};

        if (!sk1) {
            // ---- S^T = K * Q^T for both qtiles (K frags shared) ----
            f32x4 St[2][4] = {};
#pragma unroll
            for (int ks = 0; ks < 2; ++ks) {
#pragma unroll
                for (int mt = 0; mt < 4; ++mt) {
                    bf16x8 kf = *(const bf16x8*)(Kb[p] + (mt * 16 + l16) * 64 +
                                                 ((ks * 4 + quad) ^ swz) * 8);
                    St[0][mt] = __builtin_amdgcn_mfma_f32_16x16x32_bf16(kf, qf[0][ks], St[0][mt], 0, 0, 0);
                    St[1][mt] = __builtin_amdgcn_mfma_f32_16x16x32_bf16(kf, qf[1][ks], St[1][mt], 0, 0, 0);
                }
            }

            // ---- per-qtile: mask, online softmax, pack P ----
#pragma unroll
            for (int qt = 0; qt < 2; ++qt) {
                const bool skq = qt == 0 ? sk0 : sk1;
                if (skq) continue;                       // wave-uniform
                const int qn = qt == 0 ? qn0 : qn1;
                if (jt * 64 + 63 > qn) {                 // partial mask
#pragma unroll
                    for (int mt = 0; mt < 4; ++mt) {
#pragma unroll
                        for (int r = 0; r < 4; ++r) {
                            int key = jt * 64 + mt * 16 + quad * 4 + r;
                            if (key > qn + l16) St[qt][mt][r] = -__builtin_inff();
                        }
                    }
                }
                // max over 16 in-lane values + across quads
                float mx = -__builtin_inff();
#pragma unroll
                for (int mt = 0; mt < 4; ++mt) {
                    float m01 = fmaxf(St[qt][mt][0], St[qt][mt][1]);
                    float m23 = fmaxf(St[qt][mt][2], St[qt][mt][3]);
                    mx = fmaxf(mx, fmaxf(m01, m23));
                }
                mx = fmaxf(mx, __shfl_xor(mx, 16));
                mx = fmaxf(mx, __shfl_xor(mx, 32));
                float mnew = fmaxf(m_q[qt], mx);
                float al = __expf(m_q[qt] - mnew);
                m_q[qt] = mnew;
                a_q[qt] = al;
                float sum = 0.f;
#pragma unroll
                for (int mt = 0; mt < 4; ++mt) {
#pragma unroll
                    for (int r = 0; r < 4; ++r) {
                        float pv = __expf(St[qt][mt][r] - mnew);
                        St[qt][mt][r] = pv;
                        sum += pv;
                    }
                }
                sum += __shfl_xor(sum, 16);
                sum += __shfl_xor(sum, 32);
                l_q[qt] = l_q[qt] * al + sum;

                // write P row-major [query=l16][key]: 4 consecutive keys per b64
#pragma unroll
                for (int mt = 0; mt < 4; ++mt) {
                    __align__(8) __hip_bfloat16 t4[4];
                    t4[0] = __float2bfloat16(St[qt][mt][0]);
                    t4[1] = __float2bfloat16(St[qt][mt][1]);
                    t4[2] = __float2bfloat16(St[qt][mt][2]);
                    t4[3] = __float2bfloat16(St[qt][mt][3]);
                    *(uint2*)(&Ps[w][qt][l16 * 72 + mt * 16 + quad * 4]) = *(uint2*)t4;
                }
            }

            // ---- O rescale + O += P * V^T ----
#pragma unroll
            for (int qt = 0; qt < 2; ++qt) {
                const bool skq = qt == 0 ? sk0 : sk1;
                // alpha per C-layout row (query = qn + quad*4 + r), from lane quad*4+r
                float alO[4];
#pragma unroll
                for (int r = 0; r < 4; ++r) alO[r] = __shfl(a_q[qt], quad * 4 + r);
                if (skq) continue;
                bf16x8 pa0 = *(const bf16x8*)(&Ps[w][qt][l16 * 72 + quad * 8]);
                bf16x8 pa1 = *(const bf16x8*)(&Ps[w][qt][l16 * 72 + 32 + quad * 8]);
#pragma unroll
                for (int dt = 0; dt < 4; ++dt) {
#pragma unroll
                    for (int r = 0; r < 4; ++r) O[qt][dt][r] *= alO[r];
                    bf16x8 vf0 = *(const bf16x8*)(Vb[p] + (dt * 16 + l16) * 64 + ((quad) ^ swz) * 8);
                    bf16x8 vf1 = *(const bf16x8*)(Vb[p] + (dt * 16 + l16) * 64 + ((4 + quad) ^ swz) * 8);
                    O[qt][dt] = __builtin_amdgcn_mfma_f32_16x16x32_bf16(pa0, vf0, O[qt][dt], 0, 0, 0);
                    O[qt][dt] = __builtin_amdgcn_mfma_f32_16x16x32_bf16(pa1, vf1, O[qt][dt], 0, 0, 0);
                }
            }
        }
    }

    // ---- epilogue ----
#pragma unroll
    for (int qt = 0; qt < 2; ++qt) {
        float lO[4];
#pragma unroll
        for (int r = 0; r < 4; ++r) lO[r] = 1.0f / __shfl(l_q[qt], quad * 4 + r);
        const int qbase = qn0 + qt * 16 + quad * 4;
#pragma unroll
        for (int dt = 0; dt < 4; ++dt) {
#pragma unroll
            for (int r = 0; r < 4; ++r) {
                y[(size_t)(b * TT + qbase + r) * CC + h * HD + dt * 16 + l16] =
                    __float2bfloat16(O[qt][dt][r] * lO[r]);
            }
        }
    }
}

// ---------------------------------------------------------------------------
extern "C" void kernel_launch(void* const* d_in, const int* in_sizes, int n_in,
                              void* d_out, int out_size, void* d_ws, size_t ws_size,
                              hipStream_t stream) {
    const float* x      = (const float*)d_in[0];   // (B,T,C)
    const float* W_attn = (const float*)d_in[1];   // (C, 3C)
    const float* W_proj = (const float*)d_in[2];   // (C, C)
    float* out = (float*)d_out;                    // (B,T,C)

    const size_t NBT = (size_t)BB * TT;            // 8192
    __hip_bfloat16* xb   = (__hip_bfloat16*)d_ws;           // B*T*C (reused as yb)
    __hip_bfloat16* qkvb = xb + NBT * CC;                   // B*T*3C
    __hip_bfloat16* vtb  = qkvb + NBT * C3;                 // B*H*64*T
    __hip_bfloat16* Wab  = vtb + NBT * CC;                  // 3C*C  [N][K]
    __hip_bfloat16* Wpb  = Wab + (size_t)CC * C3;           // C*C   [N][K]
    __hip_bfloat16* yb   = xb;                              // reuse after qkv GEMM

    const int M = BB * TT;   // 8192

    cast_bf16x8<<<dim3((int)(NBT * CC / 2048)), 256, 0, stream>>>(x, xb);
    wtrans<<<dim3(C3 / 64, CC / 64), 256, 0, stream>>>(W_attn, Wab, CC, C3);
    wtrans<<<dim3(CC / 64, CC / 64), 256, 0, stream>>>(W_proj, Wpb, CC, CC);

    // 1) qkv = x @ W_attn  (MFMA, bf16 out)
    gemm_bt_b16<<<dim3(C3 / 128, M / 128), 256, 0, stream>>>(xb, Wab, qkvb, M, C3, CC);

    // 2) RoPE in-place on bf16 q,k (q pre-scaled by 0.125)
    rope_bf16<<<dim3((BB * TT * (CC / 2)) / 256, 2), 256, 0, stream>>>(qkvb);

    // 3) transpose V
    vtranspose<<<dim3(BB * NH * (TT / 64)), 256, 0, stream>>>(qkvb, vtb);

    // 4) MFMA flash attention v2 -> yb (bf16); 64 bh * 16 qblk = 1024 blocks
    attn_mfma2<<<dim3(BB * NH * 16), 256, 0, stream>>>(qkvb, vtb, yb);

    // 5) out = yb @ W_proj  (MFMA, fp32 out)
    gemm_bt_f32<<<dim3(CC / 128, M / 128), 256, 0, stream>>>(yb, Wpb, out, M, CC, CC);
}